// Round 1
// baseline (1368.060 us; speedup 1.0000x reference)
//
#include <hip/hip_runtime.h>
#include <hip/hip_bf16.h>
#include <math.h>

#define HH 128
#define WW 128
#define HWSZ (HH*WW)

// ---------------------------------------------------------------------------
// Direct 3x3 SAME conv. Block: 256 threads = 64 oc-lanes x 4 rows.
// Each thread computes 16 pixels along W for its (oc, row).
// IC chunked by 16 through LDS. ACT: 0=none, 1=lrelu(0.1), 2=relu.
// If IC==128, channels [64,128) come from in2 (fused concat).
// ---------------------------------------------------------------------------
template<int IC, int NOC, int ACT>
__global__ __launch_bounds__(256) void conv3x3_k(
    const float* __restrict__ in1, const float* __restrict__ in2,
    const float* __restrict__ wgt, const float* __restrict__ bias,
    float* __restrict__ out)
{
    constexpr int CHUNK = 16;
    __shared__ __align__(16) float s_in[CHUNK][6][20];   // [ic][row][col] halo tile
    __shared__ __align__(16) float s_w[CHUNK][9][64];    // [ic][tap][oc]

    const int tid = threadIdx.x;
    const int oc  = tid & 63;
    const int r   = tid >> 6;                 // 0..3 (wave-uniform)
    const int b   = blockIdx.z;
    const int r0  = blockIdx.y * 4;           // output row base
    const int cb  = blockIdx.x * 16;          // output col base

    float acc[16];
#pragma unroll
    for (int p = 0; p < 16; ++p) acc[p] = 0.f;

    for (int c0 = 0; c0 < IC; c0 += CHUNK) {
        __syncthreads();
        // ---- stage input tile: CHUNK x 6 rows x 18 cols (zero-pad OOB)
        for (int i = tid; i < CHUNK * 6 * 18; i += 256) {
            int ic  = i / 108;
            int rem = i - ic * 108;
            int row = rem / 18;
            int col = rem - row * 18;
            int gy = r0 - 1 + row;
            int gx = cb - 1 + col;
            float v = 0.f;
            if ((unsigned)gy < (unsigned)HH && (unsigned)gx < (unsigned)WW) {
                int ch = c0 + ic;
                const float* src = in1;
                if (IC == 128 && ch >= 64) { src = in2; ch -= 64; }
                v = src[((size_t)(b * 64 + ch)) * HWSZ + gy * WW + gx];
            }
            s_in[ic][row][col] = v;
        }
        // ---- stage weights for chunk: [ic][tap][oc], zero-fill oc>=NOC
        for (int i = tid; i < 64 * CHUNK * 9; i += 256) {
            int o   = i / (CHUNK * 9);
            int rem = i - o * (CHUNK * 9);
            int icc = rem / 9;
            int j   = rem - icc * 9;
            float v = 0.f;
            if (o < NOC) v = wgt[((size_t)o * IC + (c0 + icc)) * 9 + j];
            s_w[icc][j][o] = v;
        }
        __syncthreads();

        for (int ic = 0; ic < CHUNK; ++ic) {
            float vin[3][18];
#pragma unroll
            for (int dy = 0; dy < 3; ++dy) {
                const float* rp = &s_in[ic][r + dy][0];
                float4 a0 = *(const float4*)(rp + 0);
                float4 a1 = *(const float4*)(rp + 4);
                float4 a2 = *(const float4*)(rp + 8);
                float4 a3 = *(const float4*)(rp + 12);
                float2 a4 = *(const float2*)(rp + 16);
                vin[dy][0]=a0.x;  vin[dy][1]=a0.y;  vin[dy][2]=a0.z;  vin[dy][3]=a0.w;
                vin[dy][4]=a1.x;  vin[dy][5]=a1.y;  vin[dy][6]=a1.z;  vin[dy][7]=a1.w;
                vin[dy][8]=a2.x;  vin[dy][9]=a2.y;  vin[dy][10]=a2.z; vin[dy][11]=a2.w;
                vin[dy][12]=a3.x; vin[dy][13]=a3.y; vin[dy][14]=a3.z; vin[dy][15]=a3.w;
                vin[dy][16]=a4.x; vin[dy][17]=a4.y;
            }
            float wv[9];
#pragma unroll
            for (int j = 0; j < 9; ++j) wv[j] = s_w[ic][j][oc];
#pragma unroll
            for (int p = 0; p < 16; ++p) {
#pragma unroll
                for (int dy = 0; dy < 3; ++dy) {
#pragma unroll
                    for (int dx = 0; dx < 3; ++dx) {
                        acc[p] += wv[dy * 3 + dx] * vin[dy][p + dx];
                    }
                }
            }
        }
    }

    if (oc < NOC) {
        float bv = bias[oc];
        float* op = out + ((size_t)(b * NOC + oc)) * HWSZ + (r0 + r) * WW + cb;
#pragma unroll
        for (int p = 0; p < 16; ++p) {
            float v = acc[p] + bv;
            if (ACT == 1) v = (v >= 0.f) ? v : 0.1f * v;
            if (ACT == 2) v = fmaxf(v, 0.f);
            op[p] = v;
        }
    }
}

// ---------------------------------------------------------------------------
// Transpose w_dcn (O=64, C=64, 9) -> wkt[k][c][o]  (coalesced staging source)
// ---------------------------------------------------------------------------
__global__ void wtrans_k(const float* __restrict__ w, float* __restrict__ wt)
{
    int i = blockIdx.x * 256 + threadIdx.x;   // over 9*64*64 = 36864
    if (i < 9 * 64 * 64) {
        int k   = i >> 12;
        int rem = i & 4095;
        int c   = rem >> 6;
        int o   = rem & 63;
        wt[i] = w[((size_t)o * 64 + c) * 9 + k];
    }
}

// ---------------------------------------------------------------------------
// Fused DCN: bilinear-sample x at conv-predicted offsets, mask, and
// accumulate the (64o x 64c x 9k) einsum. One block per (row h, batch b).
// Sampling: 2 cgroups x 128 pix; Accumulate: 8 ogroups x 32 pixgroups (4 pix).
// ---------------------------------------------------------------------------
__global__ __launch_bounds__(256) void dcn_k(
    const float* __restrict__ x, const float* __restrict__ om,
    const float* __restrict__ wkt, const float* __restrict__ bias,
    float* __restrict__ out)
{
    __shared__ __align__(16) float s_samp[64][128];   // [c][pix]
    __shared__ __align__(16) float s_wk[64][64];      // [c][o]

    const int tid = threadIdx.x;
    const int h   = blockIdx.x;
    const int b   = blockIdx.y;

    const int og = tid >> 5;      // 0..7  -> o in [og*8, og*8+8)
    const int pg = tid & 31;      // pix in [pg*4, pg*4+4)
    const int cg = tid >> 7;      // 0..1  -> c in [cg*32, cg*32+32)
    const int pix = tid & 127;

    float acc[32];
#pragma unroll
    for (int i = 0; i < 32; ++i) acc[i] = 0.f;

    for (int k = 0; k < 9; ++k) {
        __syncthreads();
        // ---- stage per-tap weights [c][o] (coalesced from pre-transposed)
        for (int i = tid; i < 4096; i += 256) {
            ((float*)s_wk)[i] = wkt[k * 4096 + i];
        }
        // ---- bilinear sampling for this tap
        {
            const float* omb = om + (size_t)b * 27 * HWSZ + h * WW + pix;
            float oy = omb[(size_t)k * HWSZ];
            float ox = omb[(size_t)(9 + k) * HWSZ];
            float mv = omb[(size_t)(18 + k) * HWSZ];
            mv = 1.f / (1.f + expf(-mv));            // sigmoid mask
            float py = (float)(h - 1 + (k / 3)) + oy;
            float px = (float)(pix - 1 + (k % 3)) + ox;
            float y0f = floorf(py), x0f = floorf(px);
            float ly = py - y0f, lx = px - x0f;
            int y0 = (int)y0f, x0 = (int)x0f;
            int y1 = y0 + 1, x1 = x0 + 1;
            float v00 = ((unsigned)y0 < (unsigned)HH && (unsigned)x0 < (unsigned)WW) ? 1.f : 0.f;
            float v01 = ((unsigned)y0 < (unsigned)HH && (unsigned)x1 < (unsigned)WW) ? 1.f : 0.f;
            float v10 = ((unsigned)y1 < (unsigned)HH && (unsigned)x0 < (unsigned)WW) ? 1.f : 0.f;
            float v11 = ((unsigned)y1 < (unsigned)HH && (unsigned)x1 < (unsigned)WW) ? 1.f : 0.f;
            int yc0 = min(max(y0, 0), HH - 1), yc1 = min(max(y1, 0), HH - 1);
            int xc0 = min(max(x0, 0), WW - 1), xc1 = min(max(x1, 0), WW - 1);
            float w00 = (1.f - ly) * (1.f - lx) * mv * v00;
            float w01 = (1.f - ly) * lx * mv * v01;
            float w10 = ly * (1.f - lx) * mv * v10;
            float w11 = ly * lx * mv * v11;
            int i00 = yc0 * WW + xc0, i01 = yc0 * WW + xc1;
            int i10 = yc1 * WW + xc0, i11 = yc1 * WW + xc1;
            const float* xb = x + ((size_t)(b * 64 + cg * 32)) * HWSZ;
#pragma unroll
            for (int cc = 0; cc < 32; ++cc) {
                const float* xp = xb + (size_t)cc * HWSZ;
                float v = w00 * xp[i00] + w01 * xp[i01] + w10 * xp[i10] + w11 * xp[i11];
                s_samp[cg * 32 + cc][pix] = v;
            }
        }
        __syncthreads();
        // ---- accumulate einsum for this tap: 8 o x 4 pix per thread
        for (int c = 0; c < 64; ++c) {
            const float4 sv = *(const float4*)&s_samp[c][pg * 4];
            const float4 w0 = *(const float4*)&s_wk[c][og * 8];
            const float4 w1 = *(const float4*)&s_wk[c][og * 8 + 4];
            acc[0]  += w0.x * sv.x; acc[1]  += w0.x * sv.y; acc[2]  += w0.x * sv.z; acc[3]  += w0.x * sv.w;
            acc[4]  += w0.y * sv.x; acc[5]  += w0.y * sv.y; acc[6]  += w0.y * sv.z; acc[7]  += w0.y * sv.w;
            acc[8]  += w0.z * sv.x; acc[9]  += w0.z * sv.y; acc[10] += w0.z * sv.z; acc[11] += w0.z * sv.w;
            acc[12] += w0.w * sv.x; acc[13] += w0.w * sv.y; acc[14] += w0.w * sv.z; acc[15] += w0.w * sv.w;
            acc[16] += w1.x * sv.x; acc[17] += w1.x * sv.y; acc[18] += w1.x * sv.z; acc[19] += w1.x * sv.w;
            acc[20] += w1.y * sv.x; acc[21] += w1.y * sv.y; acc[22] += w1.y * sv.z; acc[23] += w1.y * sv.w;
            acc[24] += w1.z * sv.x; acc[25] += w1.z * sv.y; acc[26] += w1.z * sv.z; acc[27] += w1.z * sv.w;
            acc[28] += w1.w * sv.x; acc[29] += w1.w * sv.y; acc[30] += w1.w * sv.z; acc[31] += w1.w * sv.w;
        }
    }

    const int o0 = og * 8;
#pragma unroll
    for (int j = 0; j < 8; ++j) {
        float bv = bias[o0 + j];
        float4 v;
        v.x = acc[j * 4 + 0] + bv;
        v.y = acc[j * 4 + 1] + bv;
        v.z = acc[j * 4 + 2] + bv;
        v.w = acc[j * 4 + 3] + bv;
        *(float4*)&out[((size_t)(b * 64 + o0 + j)) * HWSZ + h * WW + pg * 4] = v;
    }
}

// ---------------------------------------------------------------------------
extern "C" void kernel_launch(void* const* d_in, const int* in_sizes, int n_in,
                              void* d_out, int out_size, void* d_ws, size_t ws_size,
                              hipStream_t stream)
{
    const float* x      = (const float*)d_in[0];
    const float* xng    = (const float*)d_in[1];
    const float* offt   = (const float*)d_in[2];
    const float* w1     = (const float*)d_in[3];
    const float* b1     = (const float*)d_in[4];
    const float* w2     = (const float*)d_in[5];
    const float* b2     = (const float*)d_in[6];
    const float* w3     = (const float*)d_in[7];
    const float* b3     = (const float*)d_in[8];
    const float* wom    = (const float*)d_in[9];
    const float* bom    = (const float*)d_in[10];
    const float* wdcn   = (const float*)d_in[11];
    const float* bdcn   = (const float*)d_in[12];
    const float* wout   = (const float*)d_in[13];
    const float* bout   = (const float*)d_in[14];

    float* out0 = (float*)d_out;                       // align_feats (4*64*HW)
    float* out1 = out0 + (size_t)4 * 64 * HWSZ;        // offset      (4*64*HW)

    float* p1  = (float*)d_ws;                         // offset_1, later om
    float* p2  = p1 + (size_t)4 * 64 * HWSZ;           // offset_2, later align
    float* wkt = p2 + (size_t)4 * 64 * HWSZ;           // transposed dcn weights

    dim3 cgrid(WW / 16, HH / 4, 4);

    // offset_1 = lrelu(conv(concat(x, x_neigh)))
    conv3x3_k<128, 64, 1><<<cgrid, 256, 0, stream>>>(x, xng, w1, b1, p1);
    // offset_2 = lrelu(conv(concat(offset_1, offset_t)))
    conv3x3_k<128, 64, 1><<<cgrid, 256, 0, stream>>>(p1, offt, w2, b2, p2);
    // offset = lrelu(conv(offset_2))  -> second output
    conv3x3_k<64, 64, 1><<<cgrid, 256, 0, stream>>>(p2, nullptr, w3, b3, out1);
    // om = conv(offset) (27 ch, no act)
    conv3x3_k<64, 27, 0><<<cgrid, 256, 0, stream>>>(out1, nullptr, wom, bom, p1);
    // transpose dcn weights to [k][c][o]
    wtrans_k<<<144, 256, 0, stream>>>(wdcn, wkt);
    // align = dcn_core(x, offsets, mask)
    dcn_k<<<dim3(HH, 4), 256, 0, stream>>>(x, p1, wkt, bdcn, p2);
    // out = relu(conv(align))  -> first output
    conv3x3_k<64, 64, 2><<<cgrid, 256, 0, stream>>>(p2, nullptr, wout, bout, out0);
}

// Round 2
// 582.529 us; speedup vs baseline: 2.3485x; 2.3485x over previous
//
#include <hip/hip_runtime.h>
#include <hip/hip_bf16.h>
#include <math.h>

#define HH 128
#define WW 128
#define HWSZ (HH*WW)

typedef __attribute__((ext_vector_type(4))) short short4v;
typedef __attribute__((ext_vector_type(8))) short bfrag;   // 8 bf16
typedef __attribute__((ext_vector_type(4))) float f4;

__device__ inline unsigned short f2bf(float v) {
    unsigned u = __builtin_bit_cast(unsigned, v);
    unsigned r = u + 0x7fffu + ((u >> 16) & 1u);
    return (unsigned short)(r >> 16);
}

// ---------------------------------------------------------------------------
// Weight prepack: fp32 W[oc][ic][3][3] -> bf16 A-fragments for
// mfma_f32_16x16x32_bf16, laid out so each lane's 8 bf16 are contiguous:
// flat = ((((oct*(NIC/64)+c64)*9+tap)*2+icc32)*64+lane)*8+j
// oc = oct*16 + (lane&15); ic = c64*64 + icc32*32 + (lane>>4)*8 + j
// ---------------------------------------------------------------------------
__device__ inline void pack_frag(const float* __restrict__ w, short* __restrict__ dst,
                                 int i, int NIC, int NOC) {
    int j     = i & 7;
    int lane  = (i >> 3) & 63;
    int icc32 = (i >> 9) & 1;
    int tap   = (i >> 10) % 9;
    int rest  = (i >> 10) / 9;          // oct*(NIC/64) + c64
    int NC    = NIC >> 6;
    int c64   = rest % NC;
    int oct   = rest / NC;
    int oc    = oct * 16 + (lane & 15);
    int ic    = c64 * 64 + icc32 * 32 + (lane >> 4) * 8 + j;
    float v = 0.f;
    if (oc < NOC) v = w[((size_t)oc * NIC + ic) * 9 + tap];
    dst[i] = (short)f2bf(v);
}

#define SZ128 73728
#define SZ64  36864

__global__ void pack_all_k(const float* __restrict__ w1, const float* __restrict__ w2,
                           const float* __restrict__ w3, const float* __restrict__ wom,
                           const float* __restrict__ wout, short* __restrict__ ap)
{
    int i = blockIdx.x * 256 + threadIdx.x;
    if      (i < SZ128)                 pack_frag(w1,  ap,                         i,                 128, 64);
    else if (i < 2*SZ128)               pack_frag(w2,  ap + SZ128,                 i - SZ128,         128, 64);
    else if (i < 2*SZ128 + SZ64)        pack_frag(w3,  ap + 2*SZ128,               i - 2*SZ128,        64, 64);
    else if (i < 2*SZ128 + 2*SZ64)      pack_frag(wom, ap + 2*SZ128 + SZ64,        i - 2*SZ128 - SZ64, 64, 27);
    else if (i < 2*SZ128 + 3*SZ64)      pack_frag(wout,ap + 2*SZ128 + 2*SZ64,      i - 2*SZ128 - 2*SZ64,64, 64);
}

// ---------------------------------------------------------------------------
// MFMA implicit-GEMM 3x3 SAME conv. Block = one (b,h) row, 256 threads.
// 4 waves = 2 oc-halves (wo) x 2 pixel-halves (wp, 64 px each).
// Wave tiles: 2 octiles(16) x 4 pixtiles(16) accumulated via 16x16x32 bf16.
// LDS: s_x[3 rows][130 cols][76 ic] bf16 (pad 76 -> 2-way banks max).
// A-fragments read from prepacked global (L2-resident).
// ---------------------------------------------------------------------------
template<int NIC, int NOC, int ACT>
__global__ __launch_bounds__(256) void conv_mfma_k(
    const float* __restrict__ in1, const float* __restrict__ in2,
    const short* __restrict__ apack, const float* __restrict__ bias,
    float* __restrict__ out)
{
    constexpr int NC = NIC / 64;
    __shared__ short s_x[3][130][76];

    const int tid  = threadIdx.x;
    const int lane = tid & 63;
    const int wv   = tid >> 6;
    const int wo   = wv & 1;          // oc-half
    const int wp   = wv >> 1;         // pixel-half
    const int n16  = lane & 15;
    const int kq   = lane >> 4;       // 0..3
    const int h    = blockIdx.x;
    const int b    = blockIdx.y;

    f4 acc[2][4];
#pragma unroll
    for (int t = 0; t < 2; ++t)
#pragma unroll
        for (int p = 0; p < 4; ++p) acc[t][p] = (f4){0.f, 0.f, 0.f, 0.f};

    const short* a_lane = apack + (size_t)lane * 8;

    for (int c64 = 0; c64 < NC; ++c64) {
        const float* src = (NIC == 128 && c64 == 1) ? in2 : in1;
        __syncthreads();
        // ---- stage 3 rows x 130 cols x 64 ic (2 ic per thread-iter), bf16
        for (int idx = tid; idx < 3 * 32 * 130; idx += 256) {
            int col = idx % 130;
            int t2  = idx / 130;
            int icp = t2 & 31;
            int dy  = t2 >> 5;
            int gy = h - 1 + dy, gx = col - 1;
            float v0 = 0.f, v1 = 0.f;
            if ((unsigned)gy < 128u && (unsigned)gx < 128u) {
                const float* p = src + ((size_t)(b * 64 + icp * 2)) * HWSZ + gy * WW + gx;
                v0 = p[0]; v1 = p[HWSZ];
            }
            unsigned pk = (unsigned)f2bf(v0) | ((unsigned)f2bf(v1) << 16);
            *(unsigned*)&s_x[dy][col][icp * 2] = pk;
        }
        __syncthreads();

#pragma unroll
        for (int tap = 0; tap < 9; ++tap) {
            const int dy = tap / 3, dx = tap % 3;
#pragma unroll
            for (int icc = 0; icc < 2; ++icc) {
                const size_t f0 = ((((size_t)(wo * 2 + 0) * NC + c64) * 9 + tap) * 2 + icc) * 512;
                const size_t f1 = ((((size_t)(wo * 2 + 1) * NC + c64) * 9 + tap) * 2 + icc) * 512;
                bfrag a0 = *(const bfrag*)(a_lane + f0);
                bfrag a1 = *(const bfrag*)(a_lane + f1);
                const int icb = icc * 32 + kq * 8;
#pragma unroll
                for (int p = 0; p < 4; ++p) {
                    const short* bp = &s_x[dy][wp * 64 + p * 16 + n16 + dx][icb];
                    short4v lo = *(const short4v*)bp;
                    short4v hi = *(const short4v*)(bp + 4);
                    bfrag bb = __builtin_shufflevector(lo, hi, 0, 1, 2, 3, 4, 5, 6, 7);
                    acc[0][p] = __builtin_amdgcn_mfma_f32_16x16x32_bf16(a0, bb, acc[0][p], 0, 0, 0);
                    acc[1][p] = __builtin_amdgcn_mfma_f32_16x16x32_bf16(a1, bb, acc[1][p], 0, 0, 0);
                }
            }
        }
    }

    // ---- epilogue: C/D layout col=lane&15, row=(lane>>4)*4+reg
#pragma unroll
    for (int t = 0; t < 2; ++t) {
#pragma unroll
        for (int r = 0; r < 4; ++r) {
            int oc = wo * 32 + t * 16 + kq * 4 + r;
            if (oc < NOC) {
                float bv = bias[oc];
#pragma unroll
                for (int p = 0; p < 4; ++p) {
                    int col = wp * 64 + p * 16 + n16;
                    float v = acc[t][p][r] + bv;
                    if (ACT == 1) v = (v >= 0.f) ? v : 0.1f * v;
                    if (ACT == 2) v = fmaxf(v, 0.f);
                    out[((size_t)(b * NOC + oc)) * HWSZ + h * WW + col] = v;
                }
            }
        }
    }
}

// ---------------------------------------------------------------------------
// Transpose w_dcn (O=64, C=64, 9) -> wkt[k][c][o]
// ---------------------------------------------------------------------------
__global__ void wtrans_k(const float* __restrict__ w, float* __restrict__ wt)
{
    int i = blockIdx.x * 256 + threadIdx.x;
    if (i < 9 * 64 * 64) {
        int k   = i >> 12;
        int rem = i & 4095;
        int c   = rem >> 6;
        int o   = rem & 63;
        wt[i] = w[((size_t)o * 64 + c) * 9 + k];
    }
}

// ---------------------------------------------------------------------------
// Fused DCN (fp32, unchanged from R1): bilinear-sample + mask + einsum.
// ---------------------------------------------------------------------------
__global__ __launch_bounds__(256) void dcn_k(
    const float* __restrict__ x, const float* __restrict__ om,
    const float* __restrict__ wkt, const float* __restrict__ bias,
    float* __restrict__ out)
{
    __shared__ __align__(16) float s_samp[64][128];
    __shared__ __align__(16) float s_wk[64][64];

    const int tid = threadIdx.x;
    const int h   = blockIdx.x;
    const int b   = blockIdx.y;

    const int og = tid >> 5;
    const int pg = tid & 31;
    const int cg = tid >> 7;
    const int pix = tid & 127;

    float acc[32];
#pragma unroll
    for (int i = 0; i < 32; ++i) acc[i] = 0.f;

    for (int k = 0; k < 9; ++k) {
        __syncthreads();
        for (int i = tid; i < 4096; i += 256) {
            ((float*)s_wk)[i] = wkt[k * 4096 + i];
        }
        {
            const float* omb = om + (size_t)b * 27 * HWSZ + h * WW + pix;
            float oy = omb[(size_t)k * HWSZ];
            float ox = omb[(size_t)(9 + k) * HWSZ];
            float mv = omb[(size_t)(18 + k) * HWSZ];
            mv = 1.f / (1.f + expf(-mv));
            float py = (float)(h - 1 + (k / 3)) + oy;
            float px = (float)(pix - 1 + (k % 3)) + ox;
            float y0f = floorf(py), x0f = floorf(px);
            float ly = py - y0f, lx = px - x0f;
            int y0 = (int)y0f, x0 = (int)x0f;
            int y1 = y0 + 1, x1 = x0 + 1;
            float v00 = ((unsigned)y0 < (unsigned)HH && (unsigned)x0 < (unsigned)WW) ? 1.f : 0.f;
            float v01 = ((unsigned)y0 < (unsigned)HH && (unsigned)x1 < (unsigned)WW) ? 1.f : 0.f;
            float v10 = ((unsigned)y1 < (unsigned)HH && (unsigned)x0 < (unsigned)WW) ? 1.f : 0.f;
            float v11 = ((unsigned)y1 < (unsigned)HH && (unsigned)x1 < (unsigned)WW) ? 1.f : 0.f;
            int yc0 = min(max(y0, 0), HH - 1), yc1 = min(max(y1, 0), HH - 1);
            int xc0 = min(max(x0, 0), WW - 1), xc1 = min(max(x1, 0), WW - 1);
            float w00 = (1.f - ly) * (1.f - lx) * mv * v00;
            float w01 = (1.f - ly) * lx * mv * v01;
            float w10 = ly * (1.f - lx) * mv * v10;
            float w11 = ly * lx * mv * v11;
            int i00 = yc0 * WW + xc0, i01 = yc0 * WW + xc1;
            int i10 = yc1 * WW + xc0, i11 = yc1 * WW + xc1;
            const float* xb = x + ((size_t)(b * 64 + cg * 32)) * HWSZ;
#pragma unroll
            for (int cc = 0; cc < 32; ++cc) {
                const float* xp = xb + (size_t)cc * HWSZ;
                float v = w00 * xp[i00] + w01 * xp[i01] + w10 * xp[i10] + w11 * xp[i11];
                s_samp[cg * 32 + cc][pix] = v;
            }
        }
        __syncthreads();
        for (int c = 0; c < 64; ++c) {
            const float4 sv = *(const float4*)&s_samp[c][pg * 4];
            const float4 w0 = *(const float4*)&s_wk[c][og * 8];
            const float4 w1 = *(const float4*)&s_wk[c][og * 8 + 4];
            acc[0]  += w0.x * sv.x; acc[1]  += w0.x * sv.y; acc[2]  += w0.x * sv.z; acc[3]  += w0.x * sv.w;
            acc[4]  += w0.y * sv.x; acc[5]  += w0.y * sv.y; acc[6]  += w0.y * sv.z; acc[7]  += w0.y * sv.w;
            acc[8]  += w0.z * sv.x; acc[9]  += w0.z * sv.y; acc[10] += w0.z * sv.z; acc[11] += w0.z * sv.w;
            acc[12] += w0.w * sv.x; acc[13] += w0.w * sv.y; acc[14] += w0.w * sv.z; acc[15] += w0.w * sv.w;
            acc[16] += w1.x * sv.x; acc[17] += w1.x * sv.y; acc[18] += w1.x * sv.z; acc[19] += w1.x * sv.w;
            acc[20] += w1.y * sv.x; acc[21] += w1.y * sv.y; acc[22] += w1.y * sv.z; acc[23] += w1.y * sv.w;
            acc[24] += w1.z * sv.x; acc[25] += w1.z * sv.y; acc[26] += w1.z * sv.z; acc[27] += w1.z * sv.w;
            acc[28] += w1.w * sv.x; acc[29] += w1.w * sv.y; acc[30] += w1.w * sv.z; acc[31] += w1.w * sv.w;
        }
    }

    const int o0 = og * 8;
#pragma unroll
    for (int j = 0; j < 8; ++j) {
        float bv = bias[o0 + j];
        float4 v;
        v.x = acc[j * 4 + 0] + bv;
        v.y = acc[j * 4 + 1] + bv;
        v.z = acc[j * 4 + 2] + bv;
        v.w = acc[j * 4 + 3] + bv;
        *(float4*)&out[((size_t)(b * 64 + o0 + j)) * HWSZ + h * WW + pg * 4] = v;
    }
}

// ---------------------------------------------------------------------------
extern "C" void kernel_launch(void* const* d_in, const int* in_sizes, int n_in,
                              void* d_out, int out_size, void* d_ws, size_t ws_size,
                              hipStream_t stream)
{
    const float* x      = (const float*)d_in[0];
    const float* xng    = (const float*)d_in[1];
    const float* offt   = (const float*)d_in[2];
    const float* w1     = (const float*)d_in[3];
    const float* b1     = (const float*)d_in[4];
    const float* w2     = (const float*)d_in[5];
    const float* b2     = (const float*)d_in[6];
    const float* w3     = (const float*)d_in[7];
    const float* b3     = (const float*)d_in[8];
    const float* wom    = (const float*)d_in[9];
    const float* bom    = (const float*)d_in[10];
    const float* wdcn   = (const float*)d_in[11];
    const float* bdcn   = (const float*)d_in[12];
    const float* wout   = (const float*)d_in[13];
    const float* bout   = (const float*)d_in[14];

    float* out0 = (float*)d_out;
    float* out1 = out0 + (size_t)4 * 64 * HWSZ;

    float* p1   = (float*)d_ws;
    float* p2   = p1 + (size_t)4 * 64 * HWSZ;
    float* wkt  = p2 + (size_t)4 * 64 * HWSZ;
    short* apk  = (short*)(wkt + 36864);

    short* a1p  = apk;
    short* a2p  = apk + SZ128;
    short* a3p  = apk + 2 * SZ128;
    short* aomp = apk + 2 * SZ128 + SZ64;
    short* aout = apk + 2 * SZ128 + 2 * SZ64;

    // pack all conv weights to MFMA fragment order (bf16)
    pack_all_k<<<(2 * SZ128 + 3 * SZ64 + 255) / 256, 256, 0, stream>>>(w1, w2, w3, wom, wout, apk);

    dim3 cgrid(HH, 4);
    // offset_1 = lrelu(conv(concat(x, x_neigh)))
    conv_mfma_k<128, 64, 1><<<cgrid, 256, 0, stream>>>(x, xng, a1p, b1, p1);
    // offset_2 = lrelu(conv(concat(offset_1, offset_t)))
    conv_mfma_k<128, 64, 1><<<cgrid, 256, 0, stream>>>(p1, offt, a2p, b2, p2);
    // offset = lrelu(conv(offset_2))  -> output 1
    conv_mfma_k<64, 64, 1><<<cgrid, 256, 0, stream>>>(p2, nullptr, a3p, b3, out1);
    // om = conv(offset), 27 ch
    conv_mfma_k<64, 27, 0><<<cgrid, 256, 0, stream>>>(out1, nullptr, aomp, bom, p1);
    // transpose dcn weights
    wtrans_k<<<144, 256, 0, stream>>>(wdcn, wkt);
    // align = dcn_core(x, offsets, mask)
    dcn_k<<<dim3(HH, 4), 256, 0, stream>>>(x, p1, wkt, bdcn, p2);
    // out = relu(conv(align)) -> output 0
    conv_mfma_k<64, 64, 2><<<cgrid, 256, 0, stream>>>(p2, nullptr, aout, bout, out0);
}

// Round 3
// 384.705 us; speedup vs baseline: 3.5561x; 1.5142x over previous
//
#include <hip/hip_runtime.h>
#include <hip/hip_bf16.h>
#include <math.h>

#define HH 128
#define WW 128
#define HWSZ (HH*WW)

typedef __attribute__((ext_vector_type(4))) short short4v;
typedef __attribute__((ext_vector_type(8))) short bfrag;   // 8 bf16
typedef __attribute__((ext_vector_type(4))) float f4;

__device__ inline unsigned short f2bf(float v) {
    unsigned u = __builtin_bit_cast(unsigned, v);
    unsigned r = u + 0x7fffu + ((u >> 16) & 1u);
    return (unsigned short)(r >> 16);
}
__device__ inline float bf2f(short s) {
    return __builtin_bit_cast(float, ((unsigned)(unsigned short)s) << 16);
}

// ---------------------------------------------------------------------------
// Weight prepack: fp32 W[oc][ic][3][3] -> bf16 A-fragments for
// mfma_f32_16x16x32_bf16:
// flat = ((((oct*(NIC/64)+c64)*9+tap)*2+icc32)*64+lane)*8+j
// oc = oct*16 + (lane&15); ic = c64*64 + icc32*32 + (lane>>4)*8 + j
// ---------------------------------------------------------------------------
__device__ inline void pack_frag(const float* __restrict__ w, short* __restrict__ dst,
                                 int i, int NIC, int NOC) {
    int j     = i & 7;
    int lane  = (i >> 3) & 63;
    int icc32 = (i >> 9) & 1;
    int tap   = (i >> 10) % 9;
    int rest  = (i >> 10) / 9;          // oct*(NIC/64) + c64
    int NC    = NIC >> 6;
    int c64   = rest % NC;
    int oct   = rest / NC;
    int oc    = oct * 16 + (lane & 15);
    int ic    = c64 * 64 + icc32 * 32 + (lane >> 4) * 8 + j;
    float v = 0.f;
    if (oc < NOC) v = w[((size_t)oc * NIC + ic) * 9 + tap];
    dst[i] = (short)f2bf(v);
}

#define SZ128 73728
#define SZ64  36864
#define SZDCN 36864

__global__ void pack_all_k(const float* __restrict__ w1, const float* __restrict__ w2,
                           const float* __restrict__ w3, const float* __restrict__ wom,
                           const float* __restrict__ wout, const float* __restrict__ wdcn,
                           short* __restrict__ ap)
{
    int i = blockIdx.x * 256 + threadIdx.x;
    if      (i < SZ128)                 pack_frag(w1,  ap,                          i,                   128, 64);
    else if (i < 2*SZ128)               pack_frag(w2,  ap + SZ128,                  i - SZ128,           128, 64);
    else if (i < 2*SZ128 + SZ64)        pack_frag(w3,  ap + 2*SZ128,                i - 2*SZ128,          64, 64);
    else if (i < 2*SZ128 + 2*SZ64)      pack_frag(wom, ap + 2*SZ128 + SZ64,         i - 2*SZ128 - SZ64,   64, 27);
    else if (i < 2*SZ128 + 3*SZ64)      pack_frag(wout,ap + 2*SZ128 + 2*SZ64,       i - 2*SZ128 - 2*SZ64, 64, 64);
    else if (i < 2*SZ128 + 3*SZ64 + SZDCN)
                                        pack_frag(wdcn,ap + 2*SZ128 + 3*SZ64,       i - 2*SZ128 - 3*SZ64, 64, 64);
}

// ---------------------------------------------------------------------------
// Transpose x (fp32, NCHW) -> xt (bf16, NHWC). Block = one (b,h) row.
// ---------------------------------------------------------------------------
__global__ __launch_bounds__(256) void xt_k(const float* __restrict__ x, short* __restrict__ xt)
{
    __shared__ short s_t[128][72];
    const int tid = threadIdx.x;
    const int h = blockIdx.x, b = blockIdx.y;
    for (int i = tid; i < 64 * 128; i += 256) {
        int c = i >> 7, w = i & 127;
        s_t[w][c] = (short)f2bf(x[((size_t)(b * 64 + c)) * HWSZ + h * WW + w]);
    }
    __syncthreads();
    for (int i = tid; i < 128 * 32; i += 256) {
        int w = i >> 5, cp = i & 31;
        unsigned pk = (unsigned)(unsigned short)s_t[w][cp * 2]
                    | ((unsigned)(unsigned short)s_t[w][cp * 2 + 1] << 16);
        *(unsigned*)&xt[(((size_t)(b * 128 + h) * 128 + w) * 64) + cp * 2] = pk;
    }
}

// ---------------------------------------------------------------------------
// MFMA implicit-GEMM 3x3 SAME conv (unchanged from R2).
// ---------------------------------------------------------------------------
template<int NIC, int NOC, int ACT>
__global__ __launch_bounds__(256) void conv_mfma_k(
    const float* __restrict__ in1, const float* __restrict__ in2,
    const short* __restrict__ apack, const float* __restrict__ bias,
    float* __restrict__ out)
{
    constexpr int NC = NIC / 64;
    __shared__ short s_x[3][130][76];

    const int tid  = threadIdx.x;
    const int lane = tid & 63;
    const int wv   = tid >> 6;
    const int wo   = wv & 1;
    const int wp   = wv >> 1;
    const int n16  = lane & 15;
    const int kq   = lane >> 4;
    const int h    = blockIdx.x;
    const int b    = blockIdx.y;

    f4 acc[2][4];
#pragma unroll
    for (int t = 0; t < 2; ++t)
#pragma unroll
        for (int p = 0; p < 4; ++p) acc[t][p] = (f4){0.f, 0.f, 0.f, 0.f};

    const short* a_lane = apack + (size_t)lane * 8;

    for (int c64 = 0; c64 < NC; ++c64) {
        const float* src = (NIC == 128 && c64 == 1) ? in2 : in1;
        __syncthreads();
        for (int idx = tid; idx < 3 * 32 * 130; idx += 256) {
            int col = idx % 130;
            int t2  = idx / 130;
            int icp = t2 & 31;
            int dy  = t2 >> 5;
            int gy = h - 1 + dy, gx = col - 1;
            float v0 = 0.f, v1 = 0.f;
            if ((unsigned)gy < 128u && (unsigned)gx < 128u) {
                const float* p = src + ((size_t)(b * 64 + icp * 2)) * HWSZ + gy * WW + gx;
                v0 = p[0]; v1 = p[HWSZ];
            }
            unsigned pk = (unsigned)f2bf(v0) | ((unsigned)f2bf(v1) << 16);
            *(unsigned*)&s_x[dy][col][icp * 2] = pk;
        }
        __syncthreads();

#pragma unroll
        for (int tap = 0; tap < 9; ++tap) {
            const int dy = tap / 3, dx = tap % 3;
#pragma unroll
            for (int icc = 0; icc < 2; ++icc) {
                const size_t f0 = ((((size_t)(wo * 2 + 0) * NC + c64) * 9 + tap) * 2 + icc) * 512;
                const size_t f1 = ((((size_t)(wo * 2 + 1) * NC + c64) * 9 + tap) * 2 + icc) * 512;
                bfrag a0 = *(const bfrag*)(a_lane + f0);
                bfrag a1 = *(const bfrag*)(a_lane + f1);
                const int icb = icc * 32 + kq * 8;
#pragma unroll
                for (int p = 0; p < 4; ++p) {
                    const short* bp = &s_x[dy][wp * 64 + p * 16 + n16 + dx][icb];
                    short4v lo = *(const short4v*)bp;
                    short4v hi = *(const short4v*)(bp + 4);
                    bfrag bb = __builtin_shufflevector(lo, hi, 0, 1, 2, 3, 4, 5, 6, 7);
                    acc[0][p] = __builtin_amdgcn_mfma_f32_16x16x32_bf16(a0, bb, acc[0][p], 0, 0, 0);
                    acc[1][p] = __builtin_amdgcn_mfma_f32_16x16x32_bf16(a1, bb, acc[1][p], 0, 0, 0);
                }
            }
        }
    }

#pragma unroll
    for (int t = 0; t < 2; ++t) {
#pragma unroll
        for (int r = 0; r < 4; ++r) {
            int oc = wo * 32 + t * 16 + kq * 4 + r;
            if (oc < NOC) {
                float bv = bias[oc];
#pragma unroll
                for (int p = 0; p < 4; ++p) {
                    int col = wp * 64 + p * 16 + n16;
                    float v = acc[t][p][r] + bv;
                    if (ACT == 1) v = (v >= 0.f) ? v : 0.1f * v;
                    if (ACT == 2) v = fmaxf(v, 0.f);
                    out[((size_t)(b * NOC + oc)) * HWSZ + h * WW + col] = v;
                }
            }
        }
    }
}

// ---------------------------------------------------------------------------
// MFMA DCN: coalesced channel-last bf16 gather + per-tap MFMA einsum.
// Block = one (b,h) row. K = 9 taps x 64 c; s_samp double-buffered per tap.
// ---------------------------------------------------------------------------
__global__ __launch_bounds__(256) void dcn_mfma_k(
    const short* __restrict__ xt, const float* __restrict__ om,
    const short* __restrict__ adcn, const float* __restrict__ bias,
    float* __restrict__ out)
{
    __shared__ __align__(16) short s_samp[2][128][72];
    __shared__ float s_py[128], s_px[128], s_m[128];

    const int tid  = threadIdx.x;
    const int lane = tid & 63;
    const int wv   = tid >> 6;
    const int wo   = wv & 1;
    const int wp   = wv >> 1;
    const int n16  = lane & 15;
    const int kq   = lane >> 4;
    const int h    = blockIdx.x;
    const int b    = blockIdx.y;

    f4 acc[2][4];
#pragma unroll
    for (int t = 0; t < 2; ++t)
#pragma unroll
        for (int p = 0; p < 4; ++p) acc[t][p] = (f4){0.f, 0.f, 0.f, 0.f};

    const short* a_lane = adcn + (size_t)lane * 8;
    const short* xb = xt + (size_t)b * HWSZ * 64;

    for (int k = 0; k < 9; ++k) {
        // ---- phase A: per-pixel params for this tap
        if (tid < 128) {
            int pix = tid;
            const float* omb = om + ((size_t)b * 27) * HWSZ + h * WW + pix;
            float oy = omb[(size_t)k * HWSZ];
            float ox = omb[(size_t)(9 + k) * HWSZ];
            float mv = omb[(size_t)(18 + k) * HWSZ];
            s_py[pix] = (float)(h - 1 + (k / 3)) + oy;
            s_px[pix] = (float)(pix - 1 + (k % 3)) + ox;
            s_m[pix]  = 1.f / (1.f + expf(-mv));
        }
        __syncthreads();
        // ---- phase B: coalesced bilinear sample (lane = channel)
        short (*buf)[72] = s_samp[k & 1];
        for (int i = 0; i < 32; ++i) {
            int pix = wv * 32 + i;
            float py = s_py[pix], px = s_px[pix], mv = s_m[pix];
            float y0f = floorf(py), x0f = floorf(px);
            float ly = py - y0f, lx = px - x0f;
            int y0 = (int)y0f, x0 = (int)x0f;
            int y1 = y0 + 1, x1 = x0 + 1;
            float v00 = ((unsigned)y0 < 128u && (unsigned)x0 < 128u) ? 1.f : 0.f;
            float v01 = ((unsigned)y0 < 128u && (unsigned)x1 < 128u) ? 1.f : 0.f;
            float v10 = ((unsigned)y1 < 128u && (unsigned)x0 < 128u) ? 1.f : 0.f;
            float v11 = ((unsigned)y1 < 128u && (unsigned)x1 < 128u) ? 1.f : 0.f;
            int yc0 = min(max(y0, 0), 127), yc1 = min(max(y1, 0), 127);
            int xc0 = min(max(x0, 0), 127), xc1 = min(max(x1, 0), 127);
            float w00 = (1.f - ly) * (1.f - lx) * mv * v00;
            float w01 = (1.f - ly) * lx * mv * v01;
            float w10 = ly * (1.f - lx) * mv * v10;
            float w11 = ly * lx * mv * v11;
            int i00 = (yc0 * WW + xc0) * 64, i01 = (yc0 * WW + xc1) * 64;
            int i10 = (yc1 * WW + xc0) * 64, i11 = (yc1 * WW + xc1) * 64;
            float v = w00 * bf2f(xb[i00 + lane]) + w01 * bf2f(xb[i01 + lane])
                    + w10 * bf2f(xb[i10 + lane]) + w11 * bf2f(xb[i11 + lane]);
            buf[pix][lane] = (short)f2bf(v);
        }
        __syncthreads();
        // ---- phase C: MFMA accumulate this tap (K=64 -> 2 ksteps)
#pragma unroll
        for (int icc = 0; icc < 2; ++icc) {
            bfrag a0 = *(const bfrag*)(a_lane + ((((size_t)(wo * 2 + 0) * 9 + k) * 2 + icc) * 512));
            bfrag a1 = *(const bfrag*)(a_lane + ((((size_t)(wo * 2 + 1) * 9 + k) * 2 + icc) * 512));
            const int icb = icc * 32 + kq * 8;
#pragma unroll
            for (int p = 0; p < 4; ++p) {
                const short* bp = &buf[wp * 64 + p * 16 + n16][icb];
                short4v lo = *(const short4v*)bp;
                short4v hi = *(const short4v*)(bp + 4);
                bfrag bb = __builtin_shufflevector(lo, hi, 0, 1, 2, 3, 4, 5, 6, 7);
                acc[0][p] = __builtin_amdgcn_mfma_f32_16x16x32_bf16(a0, bb, acc[0][p], 0, 0, 0);
                acc[1][p] = __builtin_amdgcn_mfma_f32_16x16x32_bf16(a1, bb, acc[1][p], 0, 0, 0);
            }
        }
    }

    // ---- epilogue: bias, no activation
#pragma unroll
    for (int t = 0; t < 2; ++t) {
#pragma unroll
        for (int r = 0; r < 4; ++r) {
            int oc = wo * 32 + t * 16 + kq * 4 + r;
            float bv = bias[oc];
#pragma unroll
            for (int p = 0; p < 4; ++p) {
                int col = wp * 64 + p * 16 + n16;
                out[((size_t)(b * 64 + oc)) * HWSZ + h * WW + col] = acc[t][p][r] + bv;
            }
        }
    }
}

// ---------------------------------------------------------------------------
extern "C" void kernel_launch(void* const* d_in, const int* in_sizes, int n_in,
                              void* d_out, int out_size, void* d_ws, size_t ws_size,
                              hipStream_t stream)
{
    const float* x      = (const float*)d_in[0];
    const float* xng    = (const float*)d_in[1];
    const float* offt   = (const float*)d_in[2];
    const float* w1     = (const float*)d_in[3];
    const float* b1     = (const float*)d_in[4];
    const float* w2     = (const float*)d_in[5];
    const float* b2     = (const float*)d_in[6];
    const float* w3     = (const float*)d_in[7];
    const float* b3     = (const float*)d_in[8];
    const float* wom    = (const float*)d_in[9];
    const float* bom    = (const float*)d_in[10];
    const float* wdcn   = (const float*)d_in[11];
    const float* bdcn   = (const float*)d_in[12];
    const float* wout   = (const float*)d_in[13];
    const float* bout   = (const float*)d_in[14];

    float* out0 = (float*)d_out;
    float* out1 = out0 + (size_t)4 * 64 * HWSZ;

    float* p1   = (float*)d_ws;                       // 4 MB
    float* p2   = p1 + (size_t)4 * 64 * HWSZ;         // 4 MB
    short* xt   = (short*)(p2 + (size_t)4 * 64 * HWSZ);  // 8.4 MB bf16 NHWC x
    short* apk  = xt + (size_t)4 * HWSZ * 64;

    short* a1p  = apk;
    short* a2p  = apk + SZ128;
    short* a3p  = apk + 2 * SZ128;
    short* aomp = apk + 2 * SZ128 + SZ64;
    short* aout = apk + 2 * SZ128 + 2 * SZ64;
    short* adcn = apk + 2 * SZ128 + 3 * SZ64;

    // pack all conv + dcn weights to MFMA fragment order (bf16)
    pack_all_k<<<(2 * SZ128 + 3 * SZ64 + SZDCN + 255) / 256, 256, 0, stream>>>(
        w1, w2, w3, wom, wout, wdcn, apk);
    // transpose x to channel-last bf16 for the DCN gather
    xt_k<<<dim3(HH, 4), 256, 0, stream>>>(x, xt);

    dim3 cgrid(HH, 4);
    conv_mfma_k<128, 64, 1><<<cgrid, 256, 0, stream>>>(x, xng, a1p, b1, p1);
    conv_mfma_k<128, 64, 1><<<cgrid, 256, 0, stream>>>(p1, offt, a2p, b2, p2);
    conv_mfma_k<64, 64, 1><<<cgrid, 256, 0, stream>>>(p2, nullptr, a3p, b3, out1);
    conv_mfma_k<64, 27, 0><<<cgrid, 256, 0, stream>>>(out1, nullptr, aomp, bom, p1);
    dcn_mfma_k<<<dim3(HH, 4), 256, 0, stream>>>(xt, p1, adcn, bdcn, p2);
    conv_mfma_k<64, 64, 2><<<cgrid, 256, 0, stream>>>(p2, nullptr, aout, bout, out0);
}